// Round 1
// baseline (137.134 us; speedup 1.0000x reference)
//
#include <hip/hip_runtime.h>

// Haar wavelet decomposition of channel 0 of (32,3,512,512) fp32.
// Output (32,4,256,256): bands ll,lh,hl,hh.
//
// Lane-contiguous version: lane l loads float4 at col 4*l, so every
// load instruction is one aligned 1KB segment (64 lanes x 16B), each
// input cache line touched by exactly ONE instruction (the previous
// version's 32B-strided loads touched each line from two instructions).
// Each thread covers input cols {4l..4l+3} and {256+4l..259+4l} of rows
// 2i and 2i+1 -> output col-pairs {2l,2l+1} and {128+2l,129+2l}.
// Stores are float2 (8B/lane, 512B contiguous per instruction) and
// non-temporal: the output is write-once, never re-read by this kernel,
// so don't let 33.5MB of writes thrash the 32MB L2 against the read
// stream.

typedef float f2 __attribute__((ext_vector_type(2)));
typedef float f4 __attribute__((ext_vector_type(4)));

__device__ __forceinline__ void haar2(const f4 A, const f4 C,
                                      f2& ll, f2& lh, f2& hl, f2& hh) {
    // A = {a0,b0,a1,b1} from even row; C = {c0,d0,c1,d1} from odd row.
    float sab0 = A.x + A.y, dab0 = A.x - A.y;
    float scd0 = C.x + C.y, dcd0 = C.x - C.y;
    ll.x = (sab0 + scd0) * 0.5f;
    lh.x = (sab0 - scd0) * 0.5f;
    hl.x = (dab0 + dcd0) * 0.5f;
    hh.x = (dab0 - dcd0) * 0.5f;
    float sab1 = A.z + A.w, dab1 = A.z - A.w;
    float scd1 = C.z + C.w, dcd1 = C.z - C.w;
    ll.y = (sab1 + scd1) * 0.5f;
    lh.y = (sab1 - scd1) * 0.5f;
    hl.y = (dab1 + dcd1) * 0.5f;
    hh.y = (dab1 - dcd1) * 0.5f;
}

__global__ __launch_bounds__(256) void haar_kernel(const float* __restrict__ x,
                                                   float* __restrict__ out) {
    int tid = blockIdx.x * blockDim.x + threadIdx.x;  // total 32*256*64 = 1<<19
    int l  = tid & 63;            // lane: col group
    int i  = (tid >> 6) & 255;    // output row
    int b  = tid >> 14;           // batch

    const float* r0 = x + (size_t)b * (3 * 512 * 512) + (2 * i) * 512;
    const float* r1 = r0 + 512;

    // Four loads, each a single contiguous 1KB wave segment.
    const f4 A0 = *(const f4*)(r0 + 4 * l);          // row 2i,   cols 4l..4l+3
    const f4 A1 = *(const f4*)(r0 + 256 + 4 * l);    // row 2i,   cols 256+4l..
    const f4 C0 = *(const f4*)(r1 + 4 * l);          // row 2i+1, cols 4l..
    const f4 C1 = *(const f4*)(r1 + 256 + 4 * l);    // row 2i+1, cols 256+4l..

    f2 ll0, lh0, hl0, hh0, ll1, lh1, hl1, hh1;
    haar2(A0, C0, ll0, lh0, hl0, hh0);
    haar2(A1, C1, ll1, lh1, hl1, hh1);

    // out[b][band][i][col], band stride 256*256 = 65536 floats.
    float* o = out + (size_t)b * 262144 + i * 256 + 2 * l;
    __builtin_nontemporal_store(ll0, (f2*)(o));
    __builtin_nontemporal_store(lh0, (f2*)(o + 65536));
    __builtin_nontemporal_store(hl0, (f2*)(o + 131072));
    __builtin_nontemporal_store(hh0, (f2*)(o + 196608));
    __builtin_nontemporal_store(ll1, (f2*)(o + 128));
    __builtin_nontemporal_store(lh1, (f2*)(o + 65536 + 128));
    __builtin_nontemporal_store(hl1, (f2*)(o + 131072 + 128));
    __builtin_nontemporal_store(hh1, (f2*)(o + 196608 + 128));
}

extern "C" void kernel_launch(void* const* d_in, const int* in_sizes, int n_in,
                              void* d_out, int out_size, void* d_ws, size_t ws_size,
                              hipStream_t stream) {
    const float* x = (const float*)d_in[0];
    float* out = (float*)d_out;
    haar_kernel<<<2048, 256, 0, stream>>>(x, out);
}